// Round 4
// baseline (107.896 us; speedup 1.0000x reference)
//
#include <hip/hip_runtime.h>
#include <math.h>

#define B_  8
#define S_  512
#define D_  512
#define H_  8
#define DK_ 64

typedef __attribute__((ext_vector_type(8))) short short8;
typedef __attribute__((ext_vector_type(4))) float f32x4;

#define MFMA_BF16(a, b, c) __builtin_amdgcn_mfma_f32_16x16x32_bf16(a, b, c, 0, 0, 0)

__device__ __forceinline__ unsigned bf16_rne(float x) {
    unsigned u = __float_as_uint(x);
    return (u + 0x7FFFu + ((u >> 16) & 1u)) >> 16;
}
__device__ __forceinline__ float bf16f(unsigned h) { return __uint_as_float(h << 16); }

// async global->LDS, 16B per lane; lds dest = uniform base + lane*16
__device__ __forceinline__ void glds16(const ushort* g, ushort* l) {
    __builtin_amdgcn_global_load_lds(
        (const __attribute__((address_space(1))) unsigned int*)g,
        (__attribute__((address_space(3))) unsigned int*)l,
        16, 0, 0);
}

// ---------------------------------------------------------------------------
// fp32 -> split-bf16 planes for x and the four weight matrices (one launch)
// ---------------------------------------------------------------------------
__global__ __launch_bounds__(256)
void conv_pl(const float* __restrict__ x,
             const float* __restrict__ wq, const float* __restrict__ wk,
             const float* __restrict__ wv, const float* __restrict__ wo,
             ushort* __restrict__ Xh, ushort* __restrict__ Xl,
             ushort* __restrict__ Wqh, ushort* __restrict__ Wql,
             ushort* __restrict__ Wkh, ushort* __restrict__ Wkl,
             ushort* __restrict__ Wvh, ushort* __restrict__ Wvl,
             ushort* __restrict__ Woh, ushort* __restrict__ Wol) {
    const int bid = blockIdx.x;
    const float* src; ushort* dh; ushort* dl; int i4;
    if (bid < 2048) {
        src = x; dh = Xh; dl = Xl; i4 = bid * 256 + threadIdx.x;
    } else {
        const int r = bid - 2048;
        const int wsel = r >> 8;
        src = (wsel == 0) ? wq : (wsel == 1) ? wk : (wsel == 2) ? wv : wo;
        dh  = (wsel == 0) ? Wqh : (wsel == 1) ? Wkh : (wsel == 2) ? Wvh : Woh;
        dl  = (wsel == 0) ? Wql : (wsel == 1) ? Wkl : (wsel == 2) ? Wvl : Wol;
        i4 = (r & 255) * 256 + threadIdx.x;
    }
    const float4 v = ((const float4*)src)[i4];
    unsigned h[4], l[4];
    const float* vp = &v.x;
    #pragma unroll
    for (int j = 0; j < 4; ++j) { h[j] = bf16_rne(vp[j]); l[j] = bf16_rne(vp[j] - bf16f(h[j])); }
    ((uint2*)dh)[i4] = make_uint2(h[0] | (h[1] << 16), h[2] | (h[3] << 16));
    ((uint2*)dl)[i4] = make_uint2(l[0] | (l[1] << 16), l[2] | (l[3] << 16));
}

// ---------------------------------------------------------------------------
// rel_embed [1023][512] fp32 -> per-head padded bf16 table Rg[8][1152][64]
// ---------------------------------------------------------------------------
__global__ __launch_bounds__(256)
void conv_rel(const float* __restrict__ rel, ushort* __restrict__ Rg) {
    const int idx = blockIdx.x * 256 + threadIdx.x;
    const int d2 = idx & 31;
    const int rr = (idx >> 5) % 1152;
    const int h  = idx / (1152 * 32);
    unsigned v0 = 0, v1 = 0;
    if (rr >= 64 && rr < 64 + 1023) {
        const float* s = &rel[(size_t)(rr - 64) * 512 + h * 64 + d2 * 2];
        v0 = bf16_rne(s[0]); v1 = bf16_rne(s[1]);
    }
    *(uint*)&Rg[((size_t)h * 1152 + rr) * 64 + d2 * 2] = v0 | (v1 << 16);
}

// ---------------------------------------------------------------------------
// Split-bf16 MFMA GEMM: D = X . Y^T (+bias), K=512, tile 64x64, 4 waves.
// XB: 0 = X row-major; 1 = X planes in (b,h,s,dk) blocked layout
// OM: 0 = fp32 row-major out; 2 = split planes (b,h,s,dk); 3 = V^T hi-plane only
// ---------------------------------------------------------------------------
template<int XB, int OM>
__global__ __launch_bounds__(256, 2)
void gemm_mfma(const ushort* __restrict__ Xhp, const ushort* __restrict__ Xlp,
               const ushort* __restrict__ Yh0, const ushort* __restrict__ Yl0,
               const ushort* __restrict__ Yh1, const ushort* __restrict__ Yl1,
               const float* __restrict__ bias0, const float* __restrict__ bias1,
               float* __restrict__ outF,
               ushort* __restrict__ oh0, ushort* __restrict__ ol0,
               ushort* __restrict__ oh1, ushort* __restrict__ ol1) {
    __shared__ ushort Xs[2][2][64 * 64];
    __shared__ ushort Ys[2][2][64 * 64];

    const int z = blockIdx.z;
    const ushort* Yhp = z ? Yh1 : Yh0;
    const ushort* Ylp = z ? Yl1 : Yl0;
    const float*  bias = z ? bias1 : bias0;
    ushort* ohp = z ? oh1 : oh0;
    ushort* olp = z ? ol1 : ol0;

    const int tid = threadIdx.x;
    const int w = tid >> 6, lane = tid & 63;
    const int g = lane >> 4, c = lane & 15;
    const int rloc = lane >> 3, cc8 = lane & 7;
    const int cp = cc8 ^ rloc;
    const int r0 = blockIdx.y * 64;
    const int c0 = blockIdx.x * 64;

    const f32x4 fz = {0.f, 0.f, 0.f, 0.f};
    f32x4 acc[2][2] = {{fz, fz}, {fz, fz}};

    auto stage = [&](int kt, int buf) {
        const int k0 = kt * 64;
        const ushort* gb; ushort* lb; size_t rstr;
        if (w < 2) {
            const ushort* Xp = (w == 1) ? Xlp : Xhp;
            if (XB == 0) { gb = Xp + (size_t)r0 * 512 + k0; rstr = 512; }
            else {
                const int b = r0 >> 9, s0 = r0 & 511, h = k0 >> 6;
                gb = Xp + (((size_t)(b * 8 + h)) * 512 + s0) * 64; rstr = 64;
            }
            lb = &Xs[buf][w][0];
        } else {
            gb = ((w == 2) ? Yhp : Ylp) + (size_t)c0 * 512 + k0; rstr = 512;
            lb = &Ys[buf][w - 2][0];
        }
        #pragma unroll
        for (int j = 0; j < 8; ++j)
            glds16(gb + (size_t)(j * 8 + rloc) * rstr + cp * 8, lb + j * 512);
    };

    auto compute = [&](int buf) {
        #pragma unroll
        for (int ks = 0; ks < 2; ++ks) {
            short8 axh[2], axl[2], byh[2], byl[2];
            const int wm = (w >> 1) * 32, wn = (w & 1) * 32;
            #pragma unroll
            for (int t = 0; t < 2; ++t) {
                int row = wm + t * 16 + c;
                int off = row * 64 + (((ks * 4 + g) ^ (row & 7)) * 8);
                axh[t] = *(const short8*)&Xs[buf][0][off];
                axl[t] = *(const short8*)&Xs[buf][1][off];
                row = wn + t * 16 + c;
                off = row * 64 + (((ks * 4 + g) ^ (row & 7)) * 8);
                byh[t] = *(const short8*)&Ys[buf][0][off];
                byl[t] = *(const short8*)&Ys[buf][1][off];
            }
            #pragma unroll
            for (int tm = 0; tm < 2; ++tm)
                #pragma unroll
                for (int tn = 0; tn < 2; ++tn) {
                    acc[tm][tn] = MFMA_BF16(axh[tm], byh[tn], acc[tm][tn]);
                    acc[tm][tn] = MFMA_BF16(axl[tm], byh[tn], acc[tm][tn]);
                    acc[tm][tn] = MFMA_BF16(axh[tm], byl[tn], acc[tm][tn]);
                }
        }
    };

    stage(0, 0);
    __syncthreads();
    for (int kt = 0; kt < 8; ++kt) {
        if (kt < 7) stage(kt + 1, (kt + 1) & 1);
        compute(kt & 1);
        __syncthreads();
    }

    const int wm = (w >> 1) * 32, wn = (w & 1) * 32;
    if (OM == 0) {
        #pragma unroll
        for (int tn = 0; tn < 2; ++tn) {
            const int gc = c0 + wn + tn * 16 + c;
            const float bv = bias[gc];
            #pragma unroll
            for (int tm = 0; tm < 2; ++tm)
                #pragma unroll
                for (int i = 0; i < 4; ++i) {
                    const int gr = r0 + wm + tm * 16 + g * 4 + i;
                    outF[(size_t)gr * 512 + gc] = acc[tm][tn][i] + bv;
                }
        }
    } else if (OM == 2) {
        #pragma unroll
        for (int tn = 0; tn < 2; ++tn) {
            const int gc = c0 + wn + tn * 16 + c;
            const int h = gc >> 6, dk = gc & 63;
            const float bv = bias[gc];
            #pragma unroll
            for (int tm = 0; tm < 2; ++tm)
                #pragma unroll
                for (int i = 0; i < 4; ++i) {
                    const int gr = r0 + wm + tm * 16 + g * 4 + i;
                    const int b = gr >> 9, s = gr & 511;
                    const float v = acc[tm][tn][i] + bv;
                    const unsigned hb = bf16_rne(v);
                    const size_t a = (((size_t)(b * 8 + h)) * 512 + s) * 64 + dk;
                    ohp[a] = (ushort)hb;
                    olp[a] = (ushort)bf16_rne(v - bf16f(hb));
                }
        }
    } else { // OM == 3: V^T, hi plane only
        #pragma unroll
        for (int tm = 0; tm < 2; ++tm)
            #pragma unroll
            for (int i = 0; i < 4; ++i) {
                const int gr = r0 + wm + tm * 16 + g * 4 + i;
                const int h = gr >> 6, dk = gr & 63;
                const float bv = bias[gr];
                #pragma unroll
                for (int tn = 0; tn < 2; ++tn) {
                    const int gc = c0 + wn + tn * 16 + c;
                    const int b = gc >> 9, s = gc & 511;
                    const float v = acc[tm][tn][i] + bv;
                    const size_t a = (((size_t)(b * 8 + h)) * 64 + dk) * 512 + s;
                    ohp[a] = (ushort)bf16_rne(v);
                }
            }
    }
}

// ---------------------------------------------------------------------------
// MFMA flash attention, split-K over 2 halves of the key range.
// Block = 4 waves; wave owns 16 q-rows; grid (8 qchunk, 64 bh, 2 khalf).
// Writes UNNORMALIZED fp32 partial O + per-row (m,l); combine merges halves.
// LDS 40KB -> 4 blocks/CU.
// ---------------------------------------------------------------------------
__global__ __launch_bounds__(256, 4)
void attn_mfma(const ushort* __restrict__ Qhp, const ushort* __restrict__ Qlp,
               const ushort* __restrict__ Khp, const ushort* __restrict__ Klp,
               const ushort* __restrict__ Vhp, const ushort* __restrict__ Rg,
               float* __restrict__ Op0, float* __restrict__ Op1,
               float2* __restrict__ Ml0, float2* __restrict__ Ml1) {
    __shared__ ushort Ksm[2][64 * 64];   // 16 KB [plane][key][dk], chunk-swizzled
    __shared__ ushort Vsm[64 * 64];      //  8 KB [dk][key] (V^T), swizzled
    __shared__ float  Psm[4][16 * 64];   // 16 KB per-wave P, swizzled

    const int tid  = threadIdx.x;
    const int w    = tid >> 6;
    const int lane = tid & 63;
    const int g    = lane >> 4;
    const int c    = lane & 15;
    const int rloc = lane >> 3, cc8 = lane & 7;
    const int cp   = cc8 ^ rloc;
    const int bh   = blockIdx.y;
    const int h    = bh & 7;
    const int z    = blockIdx.z;
    const int qw   = blockIdx.x * 64 + w * 16;

    float* __restrict__ Op = z ? Op1 : Op0;
    float2* __restrict__ Ml = z ? Ml1 : Ml0;

    short8 qfh[2], qfl[2];
    #pragma unroll
    for (int ks = 0; ks < 2; ++ks) {
        const size_t qi = ((size_t)bh * 512 + qw + c) * 64 + ks * 32 + g * 8;
        qfh[ks] = *(const short8*)&Qhp[qi];
        qfl[ks] = *(const short8*)&Qlp[qi];
    }

    const f32x4 fz = {0.f, 0.f, 0.f, 0.f};
    f32x4 o[4] = {fz, fz, fz, fz};
    float mreg[4], lreg[4];
    #pragma unroll
    for (int i = 0; i < 4; ++i) { mreg[i] = -INFINITY; lreg[i] = 0.f; }

    const ushort* KhB = Khp + (size_t)bh * 512 * 64;
    const ushort* KlB = Klp + (size_t)bh * 512 * 64;
    const ushort* VhB = Vhp + (size_t)bh * 64 * 512;

    for (int kt = z * 4; kt < z * 4 + 4; ++kt) {
        const int k0 = kt * 64;
        __syncthreads();
        // ---- stage: w0->Kh, w1->Kl, w2/w3 -> V^T halves ----
        if (w < 2) {
            const ushort* gb = (w == 0 ? KhB : KlB) + (size_t)k0 * 64;
            ushort* lb = &Ksm[w][0];
            #pragma unroll
            for (int j = 0; j < 8; ++j)
                glds16(gb + (size_t)(j * 8 + rloc) * 64 + cp * 8, lb + j * 512);
        } else {
            const ushort* gb = VhB + k0 + (size_t)(w - 2) * 32 * 512;
            ushort* lb = &Vsm[(w - 2) * 32 * 64];
            #pragma unroll
            for (int j = 0; j < 4; ++j)
                glds16(gb + (size_t)(j * 8 + rloc) * 512 + cp * 8, lb + j * 512);
        }
        __syncthreads();

        // ---- U tiles: U[q][delta] from global rel ----
        f32x4 u[5];
        #pragma unroll
        for (int ut = 0; ut < 5; ++ut) u[ut] = fz;
        const int rrow0 = k0 - qw + 559 + c;
        #pragma unroll
        for (int ks = 0; ks < 2; ++ks)
            #pragma unroll
            for (int ut = 0; ut < 5; ++ut) {
                const short8 rf = *(const short8*)
                    &Rg[((size_t)h * 1152 + rrow0 + ut * 16) * 64 + ks * 32 + g * 8];
                u[ut] = MFMA_BF16(qfh[ks], rf, u[ut]);
            }

        // ---- S = Q.K^T (3-term split) ----
        f32x4 s[4];
        #pragma unroll
        for (int tc = 0; tc < 4; ++tc) s[tc] = fz;
        #pragma unroll
        for (int ks = 0; ks < 2; ++ks)
            #pragma unroll
            for (int tc = 0; tc < 4; ++tc) {
                const int row = tc * 16 + c;
                const int chv = ((ks * 4 + g) ^ (row & 7)) * 8;
                const short8 kh8 = *(const short8*)&Ksm[0][row * 64 + chv];
                const short8 kl8 = *(const short8*)&Ksm[1][row * 64 + chv];
                s[tc] = MFMA_BF16(qfh[ks], kh8, s[tc]);
                s[tc] = MFMA_BF16(qfl[ks], kh8, s[tc]);
                s[tc] = MFMA_BF16(qfh[ks], kl8, s[tc]);
            }

        // ---- bias gather + online softmax + P write ----
        #pragma unroll
        for (int i = 0; i < 4; ++i) {
            const int r = g * 4 + i;
            const int srcl = (g << 4) | ((c - r) & 15);
            float sv[4];
            #pragma unroll
            for (int tc = 0; tc < 4; ++tc) {
                const float va = __shfl(u[tc + 1][i], srcl);
                const float vb = __shfl(u[tc][i], srcl);
                sv[tc] = s[tc][i] * 0.125f + ((c >= r) ? va : vb);
            }
            float tm = fmaxf(fmaxf(sv[0], sv[1]), fmaxf(sv[2], sv[3]));
            tm = fmaxf(tm, __shfl_xor(tm, 1));
            tm = fmaxf(tm, __shfl_xor(tm, 2));
            tm = fmaxf(tm, __shfl_xor(tm, 4));
            tm = fmaxf(tm, __shfl_xor(tm, 8));
            const float mold = mreg[i];
            const float mn = fmaxf(mold, tm);
            const float corr = __expf(mold - mn);
            mreg[i] = mn;
            float lacc = lreg[i] * corr;
            #pragma unroll
            for (int dt = 0; dt < 4; ++dt) o[dt][i] *= corr;
            #pragma unroll
            for (int tc = 0; tc < 4; ++tc) {
                const float p = __expf(sv[tc] - mn);
                lacc += p;
                const int col = tc * 16 + c;
                Psm[w][r * 64 + (((col >> 2) ^ r) << 2) + (col & 3)] = p;
            }
            lreg[i] = lacc;
        }
        asm volatile("s_waitcnt lgkmcnt(0)" ::: "memory");

        // ---- PV: O += P.V (2-term: V hi-plane only) ----
        #pragma unroll
        for (int ks = 0; ks < 2; ++ks) {
            const int pc0 = ks * 8 + g * 2;
            const f32x4 pa = *(const f32x4*)&Psm[w][c * 64 + ((pc0 ^ c) << 2)];
            const f32x4 pb = *(const f32x4*)&Psm[w][c * 64 + (((pc0 + 1) ^ c) << 2)];
            short8 aph, apl;
            #pragma unroll
            for (int j = 0; j < 8; ++j) {
                const float pj = (j < 4) ? pa[j] : pb[j - 4];
                const unsigned hbits = bf16_rne(pj);
                aph[j] = (short)hbits;
                apl[j] = (short)bf16_rne(pj - bf16f(hbits));
            }
            #pragma unroll
            for (int dt = 0; dt < 4; ++dt) {
                const int row = dt * 16 + c;
                const int chv = ((ks * 4 + g) ^ (row & 7)) * 8;
                const short8 vh8 = *(const short8*)&Vsm[row * 64 + chv];
                o[dt] = MFMA_BF16(aph, vh8, o[dt]);
                o[dt] = MFMA_BF16(apl, vh8, o[dt]);
            }
        }
    }

    // ---- epilogue: reduce l across 16-lane group, store partials ----
    #pragma unroll
    for (int i = 0; i < 4; ++i) {
        float ls = lreg[i];
        ls += __shfl_xor(ls, 1);
        ls += __shfl_xor(ls, 2);
        ls += __shfl_xor(ls, 4);
        ls += __shfl_xor(ls, 8);
        const int r = g * 4 + i;
        const size_t rowi = (size_t)bh * 512 + qw + r;
        if (c == 0) Ml[rowi] = make_float2(mreg[i], ls);
        #pragma unroll
        for (int dt = 0; dt < 4; ++dt)
            Op[rowi * 64 + dt * 16 + c] = o[dt][i];
    }
}

// ---------------------------------------------------------------------------
// merge the two split-K halves, normalize, emit split-bf16 O planes
// ---------------------------------------------------------------------------
__global__ __launch_bounds__(256)
void attn_combine(const float* __restrict__ Op0, const float* __restrict__ Op1,
                  const float2* __restrict__ Ml0, const float2* __restrict__ Ml1,
                  ushort* __restrict__ Oh, ushort* __restrict__ Ol) {
    const int tid = threadIdx.x;
    const int row = blockIdx.x * 64 + (tid >> 2);
    const int d0 = (tid & 3) * 16;
    const float2 a = Ml0[row], b = Ml1[row];
    const float m = fmaxf(a.x, b.x);
    float w0 = __expf(a.x - m), w1 = __expf(b.x - m);
    const float inv = 1.0f / (a.y * w0 + b.y * w1);
    w0 *= inv; w1 *= inv;
    const size_t base = (size_t)row * 64 + d0;
    #pragma unroll
    for (int j = 0; j < 4; ++j) {
        const float4 v0 = *(const float4*)&Op0[base + j * 4];
        const float4 v1 = *(const float4*)&Op1[base + j * 4];
        float vv[4] = {v0.x * w0 + v1.x * w1, v0.y * w0 + v1.y * w1,
                       v0.z * w0 + v1.z * w1, v0.w * w0 + v1.w * w1};
        unsigned hb[4], lb4[4];
        #pragma unroll
        for (int q = 0; q < 4; ++q) {
            hb[q] = bf16_rne(vv[q]);
            lb4[q] = bf16_rne(vv[q] - bf16f(hb[q]));
        }
        *(uint2*)&Oh[base + j * 4] = make_uint2(hb[0] | (hb[1] << 16), hb[2] | (hb[3] << 16));
        *(uint2*)&Ol[base + j * 4] = make_uint2(lb4[0] | (lb4[1] << 16), lb4[2] | (lb4[3] << 16));
    }
}

// ---------------------------------------------------------------------------
extern "C" void kernel_launch(void* const* d_in, const int* in_sizes, int n_in,
                              void* d_out, int out_size, void* d_ws, size_t ws_size,
                              hipStream_t stream) {
    const float* x   = (const float*)d_in[0];
    const float* Wq  = (const float*)d_in[1];
    const float* bq  = (const float*)d_in[2];
    const float* Wk  = (const float*)d_in[3];
    const float* bk  = (const float*)d_in[4];
    const float* Wv  = (const float*)d_in[5];
    const float* bv  = (const float*)d_in[6];
    const float* Wo  = (const float*)d_in[7];
    const float* bo  = (const float*)d_in[8];
    const float* rel = (const float*)d_in[9];
    float* out = (float*)d_out;

    const size_t NP = (size_t)B_ * H_ * S_ * DK_;   // 2,097,152
    const size_t WP = (size_t)D_ * D_;              //   262,144
    ushort* Xh  = (ushort*)d_ws;
    ushort* Xl  = Xh + NP;
    ushort* Wqh = Xl + NP;
    ushort* Wql = Wqh + WP;
    ushort* Wkh = Wql + WP;
    ushort* Wkl = Wkh + WP;
    ushort* Wvh = Wkl + WP;
    ushort* Wvl = Wvh + WP;
    ushort* Woh = Wvl + WP;
    ushort* Wol = Woh + WP;
    ushort* Qh  = Wol + WP;
    ushort* Ql  = Qh + NP;
    ushort* Kh  = Ql + NP;
    ushort* Kl  = Kh + NP;
    ushort* Vh  = Kl + NP;
    ushort* Rg  = Vh + NP;                    // 589,824 ushorts
    float*  Op1 = (float*)(Rg + 589824);      // NP floats
    float2* Ml0 = (float2*)(Op1 + NP);        // 32768 float2
    float2* Ml1 = Ml0 + 32768;
    float*  Op0 = (float*)d_ws;               // overlays Xh,Xl (dead after V GEMM)

    conv_pl<<<3072, 256, 0, stream>>>(x, Wq, Wk, Wv, Wo,
                                      Xh, Xl, Wqh, Wql, Wkh, Wkl, Wvh, Wvl, Woh, Wol);
    conv_rel<<<1152, 256, 0, stream>>>(rel, Rg);

    // Q and K projections fused via grid.z
    gemm_mfma<0, 2><<<dim3(8, 64, 2), 256, 0, stream>>>(
        Xh, Xl, Wqh, Wql, Wkh, Wkl, bq, bk, nullptr, Qh, Ql, Kh, Kl);
    // V projection, operand-swapped -> V^T hi plane
    gemm_mfma<0, 3><<<dim3(64, 8, 1), 256, 0, stream>>>(
        Wvh, Wvl, Xh, Xl, nullptr, nullptr, bv, nullptr, nullptr, Vh, nullptr, nullptr, nullptr);

    // split-K attention: partials (Op0 overlays X planes, now dead)
    attn_mfma<<<dim3(8, 64, 2), 256, 0, stream>>>(
        Qh, Ql, Kh, Kl, Vh, Rg, Op0, Op1, Ml0, Ml1);

    // combine halves -> O planes (overlay Kh,Kl, dead after attn)
    attn_combine<<<512, 256, 0, stream>>>(Op0, Op1, Ml0, Ml1, Kh, Kl);

    // output projection reads O planes (blocked layout), writes fp32
    gemm_mfma<1, 0><<<dim3(8, 64, 1), 256, 0, stream>>>(
        Kh, Kl, Woh, Wol, nullptr, nullptr, bo, nullptr, out, nullptr, nullptr, nullptr, nullptr);
}

// Round 5
// 102.378 us; speedup vs baseline: 1.0539x; 1.0539x over previous
//
#include <hip/hip_runtime.h>
#include <math.h>

#define B_  8
#define S_  512
#define D_  512
#define H_  8
#define DK_ 64

typedef __attribute__((ext_vector_type(8))) short short8;
typedef __attribute__((ext_vector_type(4))) float f32x4;

#define MFMA_BF16(a, b, c) __builtin_amdgcn_mfma_f32_16x16x32_bf16(a, b, c, 0, 0, 0)

__device__ __forceinline__ unsigned bf16_rne(float x) {
    unsigned u = __float_as_uint(x);
    return (u + 0x7FFFu + ((u >> 16) & 1u)) >> 16;
}
__device__ __forceinline__ float bf16f(unsigned h) { return __uint_as_float(h << 16); }

// async global->LDS, 16B per lane; lds dest = uniform base + lane*16
__device__ __forceinline__ void glds16(const ushort* g, ushort* l) {
    __builtin_amdgcn_global_load_lds(
        (const __attribute__((address_space(1))) unsigned int*)g,
        (__attribute__((address_space(3))) unsigned int*)l,
        16, 0, 0);
}

// ---------------------------------------------------------------------------
// fp32 -> split-bf16 planes for x and the four weight matrices (one launch)
// ---------------------------------------------------------------------------
__global__ __launch_bounds__(256)
void conv_pl(const float* __restrict__ x,
             const float* __restrict__ wq, const float* __restrict__ wk,
             const float* __restrict__ wv, const float* __restrict__ wo,
             ushort* __restrict__ Xh, ushort* __restrict__ Xl,
             ushort* __restrict__ Wqh, ushort* __restrict__ Wql,
             ushort* __restrict__ Wkh, ushort* __restrict__ Wkl,
             ushort* __restrict__ Wvh, ushort* __restrict__ Wvl,
             ushort* __restrict__ Woh, ushort* __restrict__ Wol) {
    const int bid = blockIdx.x;
    const float* src; ushort* dh; ushort* dl; int i4;
    if (bid < 2048) {
        src = x; dh = Xh; dl = Xl; i4 = bid * 256 + threadIdx.x;
    } else {
        const int r = bid - 2048;
        const int wsel = r >> 8;
        src = (wsel == 0) ? wq : (wsel == 1) ? wk : (wsel == 2) ? wv : wo;
        dh  = (wsel == 0) ? Wqh : (wsel == 1) ? Wkh : (wsel == 2) ? Wvh : Woh;
        dl  = (wsel == 0) ? Wql : (wsel == 1) ? Wkl : (wsel == 2) ? Wvl : Wol;
        i4 = (r & 255) * 256 + threadIdx.x;
    }
    const float4 v = ((const float4*)src)[i4];
    unsigned h[4], l[4];
    const float* vp = &v.x;
    #pragma unroll
    for (int j = 0; j < 4; ++j) { h[j] = bf16_rne(vp[j]); l[j] = bf16_rne(vp[j] - bf16f(h[j])); }
    ((uint2*)dh)[i4] = make_uint2(h[0] | (h[1] << 16), h[2] | (h[3] << 16));
    ((uint2*)dl)[i4] = make_uint2(l[0] | (l[1] << 16), l[2] | (l[3] << 16));
}

// ---------------------------------------------------------------------------
// rel_embed [1023][512] fp32 -> per-head padded bf16 table Rg[8][1152][64]
// ---------------------------------------------------------------------------
__global__ __launch_bounds__(256)
void conv_rel(const float* __restrict__ rel, ushort* __restrict__ Rg) {
    const int idx = blockIdx.x * 256 + threadIdx.x;
    const int d2 = idx & 31;
    const int rr = (idx >> 5) % 1152;
    const int h  = idx / (1152 * 32);
    unsigned v0 = 0, v1 = 0;
    if (rr >= 64 && rr < 64 + 1023) {
        const float* s = &rel[(size_t)(rr - 64) * 512 + h * 64 + d2 * 2];
        v0 = bf16_rne(s[0]); v1 = bf16_rne(s[1]);
    }
    *(uint*)&Rg[((size_t)h * 1152 + rr) * 64 + d2 * 2] = v0 | (v1 << 16);
}

// ---------------------------------------------------------------------------
// Split-bf16 MFMA GEMM: D = X . Y^T (+bias)*scale, K=512, tile 64x64, 4 waves.
// XB: 0 = X row-major; 1 = X planes in (b,h,s,dk) blocked layout
// OM: 0 = fp32 row-major out; 2 = split planes (b,h,s,dk); 3 = V^T hi-plane only
// ---------------------------------------------------------------------------
template<int XB, int OM>
__global__ __launch_bounds__(256, 2)
void gemm_mfma(const ushort* __restrict__ Xhp, const ushort* __restrict__ Xlp,
               const ushort* __restrict__ Yh0, const ushort* __restrict__ Yl0,
               const ushort* __restrict__ Yh1, const ushort* __restrict__ Yl1,
               const float* __restrict__ bias0, const float* __restrict__ bias1,
               float scale0, float scale1,
               float* __restrict__ outF,
               ushort* __restrict__ oh0, ushort* __restrict__ ol0,
               ushort* __restrict__ oh1, ushort* __restrict__ ol1) {
    __shared__ ushort Xs[2][2][64 * 64];
    __shared__ ushort Ys[2][2][64 * 64];

    const int z = blockIdx.z;
    const ushort* Yhp = z ? Yh1 : Yh0;
    const ushort* Ylp = z ? Yl1 : Yl0;
    const float*  bias = z ? bias1 : bias0;
    const float   scale = z ? scale1 : scale0;
    ushort* ohp = z ? oh1 : oh0;
    ushort* olp = z ? ol1 : ol0;

    const int tid = threadIdx.x;
    const int w = tid >> 6, lane = tid & 63;
    const int g = lane >> 4, c = lane & 15;
    const int rloc = lane >> 3, cc8 = lane & 7;
    const int cp = cc8 ^ rloc;
    const int r0 = blockIdx.y * 64;
    const int c0 = blockIdx.x * 64;

    const f32x4 fz = {0.f, 0.f, 0.f, 0.f};
    f32x4 acc[2][2] = {{fz, fz}, {fz, fz}};

    auto stage = [&](int kt, int buf) {
        const int k0 = kt * 64;
        const ushort* gb; ushort* lb; size_t rstr;
        if (w < 2) {
            const ushort* Xp = (w == 1) ? Xlp : Xhp;
            if (XB == 0) { gb = Xp + (size_t)r0 * 512 + k0; rstr = 512; }
            else {
                const int b = r0 >> 9, s0 = r0 & 511, h = k0 >> 6;
                gb = Xp + (((size_t)(b * 8 + h)) * 512 + s0) * 64; rstr = 64;
            }
            lb = &Xs[buf][w][0];
        } else {
            gb = ((w == 2) ? Yhp : Ylp) + (size_t)c0 * 512 + k0; rstr = 512;
            lb = &Ys[buf][w - 2][0];
        }
        #pragma unroll
        for (int j = 0; j < 8; ++j)
            glds16(gb + (size_t)(j * 8 + rloc) * rstr + cp * 8, lb + j * 512);
    };

    auto compute = [&](int buf) {
        #pragma unroll
        for (int ks = 0; ks < 2; ++ks) {
            short8 axh[2], axl[2], byh[2], byl[2];
            const int wm = (w >> 1) * 32, wn = (w & 1) * 32;
            #pragma unroll
            for (int t = 0; t < 2; ++t) {
                int row = wm + t * 16 + c;
                int off = row * 64 + (((ks * 4 + g) ^ (row & 7)) * 8);
                axh[t] = *(const short8*)&Xs[buf][0][off];
                axl[t] = *(const short8*)&Xs[buf][1][off];
                row = wn + t * 16 + c;
                off = row * 64 + (((ks * 4 + g) ^ (row & 7)) * 8);
                byh[t] = *(const short8*)&Ys[buf][0][off];
                byl[t] = *(const short8*)&Ys[buf][1][off];
            }
            #pragma unroll
            for (int tm = 0; tm < 2; ++tm)
                #pragma unroll
                for (int tn = 0; tn < 2; ++tn) {
                    acc[tm][tn] = MFMA_BF16(axh[tm], byh[tn], acc[tm][tn]);
                    acc[tm][tn] = MFMA_BF16(axl[tm], byh[tn], acc[tm][tn]);
                    acc[tm][tn] = MFMA_BF16(axh[tm], byl[tn], acc[tm][tn]);
                }
        }
    };

    stage(0, 0);
    __syncthreads();
    for (int kt = 0; kt < 8; ++kt) {
        if (kt < 7) stage(kt + 1, (kt + 1) & 1);
        compute(kt & 1);
        __syncthreads();
    }

    const int wm = (w >> 1) * 32, wn = (w & 1) * 32;
    if (OM == 0) {
        #pragma unroll
        for (int tn = 0; tn < 2; ++tn) {
            const int gc = c0 + wn + tn * 16 + c;
            const float bv = bias[gc];
            #pragma unroll
            for (int tm = 0; tm < 2; ++tm)
                #pragma unroll
                for (int i = 0; i < 4; ++i) {
                    const int gr = r0 + wm + tm * 16 + g * 4 + i;
                    outF[(size_t)gr * 512 + gc] = acc[tm][tn][i] + bv;
                }
        }
    } else if (OM == 2) {
        #pragma unroll
        for (int tn = 0; tn < 2; ++tn) {
            const int gc = c0 + wn + tn * 16 + c;
            const int h = gc >> 6, dk = gc & 63;
            const float bv = bias[gc];
            #pragma unroll
            for (int tm = 0; tm < 2; ++tm)
                #pragma unroll
                for (int i = 0; i < 4; ++i) {
                    const int gr = r0 + wm + tm * 16 + g * 4 + i;
                    const int b = gr >> 9, s = gr & 511;
                    const float v = (acc[tm][tn][i] + bv) * scale;
                    const unsigned hb = bf16_rne(v);
                    const size_t a = (((size_t)(b * 8 + h)) * 512 + s) * 64 + dk;
                    ohp[a] = (ushort)hb;
                    olp[a] = (ushort)bf16_rne(v - bf16f(hb));
                }
        }
    } else { // OM == 3: V^T, hi plane only
        #pragma unroll
        for (int tm = 0; tm < 2; ++tm)
            #pragma unroll
            for (int i = 0; i < 4; ++i) {
                const int gr = r0 + wm + tm * 16 + g * 4 + i;
                const int h = gr >> 6, dk = gr & 63;
                const float bv = bias[gr];
                #pragma unroll
                for (int tn = 0; tn < 2; ++tn) {
                    const int gc = c0 + wn + tn * 16 + c;
                    const int b = gc >> 9, s = gc & 511;
                    const float v = acc[tm][tn][i] + bv;
                    const size_t a = (((size_t)(b * 8 + h)) * 64 + dk) * 512 + s;
                    ohp[a] = (ushort)bf16_rne(v);
                }
            }
    }
}

// ---------------------------------------------------------------------------
// MFMA flash attention, LANE-LOCAL softmax via S^T = mfma(K, Q) with a
// permuted key-row assignment so the P row lands directly in the PV B-frag:
//   key(tc, r) = 32*(tc&1) + 8*(r>>2) + 4*(tc>>1) + (r&3)
// Lane (g,c) owns q-row (qw+c); its 16 S values cover keys {8g..8g+7} u
// {32+8g..32+8g+7} = exactly the B-frag k-slots of PV. Zero-shuffle softmax
// (2 shfl_xor for the cross-g row reduce), no P LDS round-trip.
// Bias via per-wave bf16 U-buffer (U = Q.rel^T tiles, direct delta indexing).
// K pre-scaled by 1/8 at projection. Split-K x2, partials + (m,l) out.
// ---------------------------------------------------------------------------
__global__ __launch_bounds__(256, 3)
void attn_mfma(const ushort* __restrict__ Qhp, const ushort* __restrict__ Qlp,
               const ushort* __restrict__ Khp, const ushort* __restrict__ Klp,
               const ushort* __restrict__ Vhp, const ushort* __restrict__ Rg,
               float* __restrict__ Op0, float* __restrict__ Op1,
               float2* __restrict__ Ml0, float2* __restrict__ Ml1) {
    __shared__ ushort Ksm[2][64 * 64];   // 16 KB, key rows PERMUTED via key()
    __shared__ ushort Vsm[64 * 64];      //  8 KB [dk][key] (V^T), linear keys
    __shared__ ushort Usm[4][16 * 86];   // 11 KB per-wave bias rows [q_loc][du]

    const int tid  = threadIdx.x;
    const int w    = tid >> 6;
    const int lane = tid & 63;
    const int g    = lane >> 4;
    const int c    = lane & 15;
    const int rloc = lane >> 3, cc8 = lane & 7;
    const int bh   = blockIdx.y;
    const int h    = bh & 7;
    const int z    = blockIdx.z;
    const int qw   = blockIdx.x * 64 + w * 16;

    float* __restrict__ Op = z ? Op1 : Op0;
    float2* __restrict__ Ml = z ? Ml1 : Ml0;

    // Q fragments (B-operand layout == A layout): q = qw + c
    short8 qfh[2], qfl[2];
    #pragma unroll
    for (int ks = 0; ks < 2; ++ks) {
        const size_t qi = ((size_t)bh * 512 + qw + c) * 64 + ks * 32 + g * 8;
        qfh[ks] = *(const short8*)&Qhp[qi];
        qfl[ks] = *(const short8*)&Qlp[qi];
    }

    const f32x4 fz = {0.f, 0.f, 0.f, 0.f};
    f32x4 o[4] = {fz, fz, fz, fz};      // O^T: row d = 16dt+4g+i, col q = c
    float m = -INFINITY, l = 0.f;       // per-lane: q = qw + c

    const ushort* KhB = Khp + (size_t)bh * 512 * 64;
    const ushort* KlB = Klp + (size_t)bh * 512 * 64;
    const ushort* VhB = Vhp + (size_t)bh * 64 * 512;

    for (int kt = z * 4; kt < z * 4 + 4; ++kt) {
        const int k0 = kt * 64;
        __syncthreads();
        // ---- stage: w0->Kh, w1->Kl (key-permuted), w2/w3 -> V^T halves ----
        if (w < 2) {
            const ushort* gb = (w == 0) ? KhB : KlB;
            ushort* lb = &Ksm[w][0];
            #pragma unroll
            for (int j = 0; j < 8; ++j) {
                const int row = j * 8 + rloc;              // LDS row
                const int tcq = row >> 4, cq = row & 15;
                const int key = ((tcq & 1) << 5) + ((cq >> 2) << 3)
                              + ((tcq >> 1) << 2) + (cq & 3);
                glds16(gb + (size_t)(k0 + key) * 64 + (cc8 ^ rloc) * 8,
                       lb + j * 512);
            }
        } else {
            const ushort* gb = VhB + k0 + (size_t)(w - 2) * 32 * 512;
            ushort* lb = &Vsm[(w - 2) * 32 * 64];
            #pragma unroll
            for (int j = 0; j < 4; ++j)
                glds16(gb + (size_t)(j * 8 + rloc) * 512 + (cc8 ^ rloc) * 8,
                       lb + j * 512);
        }
        __syncthreads();

        // ---- U tiles: U[q][delta] (1-term), write to per-wave bias rows ----
        f32x4 u[5];
        #pragma unroll
        for (int ut = 0; ut < 5; ++ut) u[ut] = fz;
        const int rrow0 = k0 - qw + 560 + c;
        #pragma unroll
        for (int ks = 0; ks < 2; ++ks)
            #pragma unroll
            for (int ut = 0; ut < 5; ++ut) {
                const short8 rf = *(const short8*)
                    &Rg[((size_t)h * 1152 + rrow0 + ut * 16) * 64 + ks * 32 + g * 8];
                u[ut] = MFMA_BF16(qfh[ks], rf, u[ut]);
            }
        #pragma unroll
        for (int ut = 0; ut < 5; ++ut)
            #pragma unroll
            for (int i = 0; i < 4; ++i)
                Usm[w][(g * 4 + i) * 86 + c + ut * 16] = (ushort)bf16_rne(u[ut][i]);

        // ---- S^T tiles: mfma(A=K permuted rows, B=Q), 3-term split ----
        f32x4 st[4];
        #pragma unroll
        for (int tc = 0; tc < 4; ++tc) st[tc] = fz;
        #pragma unroll
        for (int ks = 0; ks < 2; ++ks)
            #pragma unroll
            for (int tc = 0; tc < 4; ++tc) {
                const int row = tc * 16 + c;
                const int chv = ((ks * 4 + g) ^ (row & 7)) * 8;
                const short8 kh8 = *(const short8*)&Ksm[0][row * 64 + chv];
                const short8 kl8 = *(const short8*)&Ksm[1][row * 64 + chv];
                st[tc] = MFMA_BF16(kh8, qfh[ks], st[tc]);
                st[tc] = MFMA_BF16(kh8, qfl[ks], st[tc]);
                st[tc] = MFMA_BF16(kl8, qfh[ks], st[tc]);
            }

        asm volatile("s_waitcnt lgkmcnt(0)" ::: "memory");  // U writes visible

        // ---- bias add (scalar LDS reads, direct delta indexing) ----
        #pragma unroll
        for (int tc = 0; tc < 4; ++tc)
            #pragma unroll
            for (int i = 0; i < 4; ++i) {
                const int key = ((tc & 1) << 5) + 8 * g + ((tc >> 1) << 2) + i;
                st[tc][i] += bf16f(Usm[w][c * 85 + key + 15]);
            }

        // ---- lane-local online softmax ----
        float tm = fmaxf(fmaxf(st[0][0], st[0][1]), fmaxf(st[0][2], st[0][3]));
        #pragma unroll
        for (int tc = 1; tc < 4; ++tc) {
            const float t2 = fmaxf(fmaxf(st[tc][0], st[tc][1]),
                                   fmaxf(st[tc][2], st[tc][3]));
            tm = fmaxf(tm, t2);
        }
        tm = fmaxf(tm, __shfl_xor(tm, 16));
        tm = fmaxf(tm, __shfl_xor(tm, 32));
        const float mn = fmaxf(m, tm);
        const float corr = __expf(m - mn);      // first tile: exp(-inf)=0
        m = mn;
        l *= corr;
        #pragma unroll
        for (int dt = 0; dt < 4; ++dt) o[dt] *= corr;

        uint pk[4][2];
        #pragma unroll
        for (int tc = 0; tc < 4; ++tc) {
            const float p0 = __expf(st[tc][0] - mn);
            const float p1 = __expf(st[tc][1] - mn);
            const float p2 = __expf(st[tc][2] - mn);
            const float p3 = __expf(st[tc][3] - mn);
            l += (p0 + p1) + (p2 + p3);
            pk[tc][0] = bf16_rne(p0) | (bf16_rne(p1) << 16);
            pk[tc][1] = bf16_rne(p2) | (bf16_rne(p3) << 16);
        }

        // ---- PV: O^T += mfma(A=V^T, B=P^T); B-frag is lane-local! ----
        #pragma unroll
        for (int ks = 0; ks < 2; ++ks) {
            union { uint u4[4]; short8 s8; } pb;
            pb.u4[0] = pk[ks][0];
            pb.u4[1] = pk[ks][1];
            pb.u4[2] = pk[ks + 2][0];
            pb.u4[3] = pk[ks + 2][1];
            #pragma unroll
            for (int dt = 0; dt < 4; ++dt) {
                const int row = dt * 16 + c;
                const int chv = ((ks * 4 + g) ^ (row & 7)) * 8;
                const short8 vh8 = *(const short8*)&Vsm[row * 64 + chv];
                o[dt] = MFMA_BF16(vh8, pb.s8, o[dt]);
            }
        }
    }

    // ---- epilogue: reduce l over g-groups, store O^T partial + (m,l) ----
    float lt = l;
    lt += __shfl_xor(lt, 16);
    lt += __shfl_xor(lt, 32);
    if (lane < 16) Ml[(size_t)bh * 512 + qw + c] = make_float2(m, lt);
    #pragma unroll
    for (int dt = 0; dt < 4; ++dt)
        #pragma unroll
        for (int i = 0; i < 4; ++i)
            Op[((size_t)bh * 64 + dt * 16 + g * 4 + i) * 512 + qw + c] = o[dt][i];
}

// ---------------------------------------------------------------------------
// merge split-K halves, transpose O^T -> (b,h,s,dk), emit split-bf16 O planes
// grid (8 s-chunks, 64 bh)
// ---------------------------------------------------------------------------
__global__ __launch_bounds__(256)
void attn_combine(const float* __restrict__ Op0, const float* __restrict__ Op1,
                  const float2* __restrict__ Ml0, const float2* __restrict__ Ml1,
                  ushort* __restrict__ Oh, ushort* __restrict__ Ol) {
    __shared__ float L0[64][67];
    __shared__ float L1[64][67];
    const int t = threadIdx.x;
    const int bh = blockIdx.y;
    const int s0 = blockIdx.x * 64;
    #pragma unroll
    for (int j = 0; j < 4; ++j) {
        const int d = (t >> 4) + j * 16;
        const int c4 = (t & 15) * 4;
        const size_t ga = ((size_t)bh * 64 + d) * 512 + s0 + c4;
        *(float4*)&L0[d][c4] = *(const float4*)&Op0[ga];
        *(float4*)&L1[d][c4] = *(const float4*)&Op1[ga];
    }
    __syncthreads();
    const int sl = t >> 2;
    const int d0 = (t & 3) * 16;
    const float2 a = Ml0[(size_t)bh * 512 + s0 + sl];
    const float2 b = Ml1[(size_t)bh * 512 + s0 + sl];
    const float mm = fmaxf(a.x, b.x);
    float w0 = __expf(a.x - mm), w1 = __expf(b.x - mm);
    const float inv = 1.0f / (a.y * w0 + b.y * w1);
    w0 *= inv; w1 *= inv;
    const size_t ob = ((size_t)bh * 512 + s0 + sl) * 64 + d0;
    #pragma unroll
    for (int q = 0; q < 4; ++q) {
        unsigned hb[4], lb4[4];
        #pragma unroll
        for (int e = 0; e < 4; ++e) {
            const int dd = q * 4 + e;
            const float v = L0[d0 + dd][sl] * w0 + L1[d0 + dd][sl] * w1;
            hb[e] = bf16_rne(v);
            lb4[e] = bf16_rne(v - bf16f(hb[e]));
        }
        *(uint2*)&Oh[ob + q * 4] = make_uint2(hb[0] | (hb[1] << 16), hb[2] | (hb[3] << 16));
        *(uint2*)&Ol[ob + q * 4] = make_uint2(lb4[0] | (lb4[1] << 16), lb4[2] | (lb4[3] << 16));
    }
}

// ---------------------------------------------------------------------------
extern "C" void kernel_launch(void* const* d_in, const int* in_sizes, int n_in,
                              void* d_out, int out_size, void* d_ws, size_t ws_size,
                              hipStream_t stream) {
    const float* x   = (const float*)d_in[0];
    const float* Wq  = (const float*)d_in[1];
    const float* bq  = (const float*)d_in[2];
    const float* Wk  = (const float*)d_in[3];
    const float* bk  = (const float*)d_in[4];
    const float* Wv  = (const float*)d_in[5];
    const float* bv  = (const float*)d_in[6];
    const float* Wo  = (const float*)d_in[7];
    const float* bo  = (const float*)d_in[8];
    const float* rel = (const float*)d_in[9];
    float* out = (float*)d_out;

    const size_t NP = (size_t)B_ * H_ * S_ * DK_;   // 2,097,152
    const size_t WP = (size_t)D_ * D_;              //   262,144
    ushort* Xh  = (ushort*)d_ws;
    ushort* Xl  = Xh + NP;
    ushort* Wqh = Xl + NP;
    ushort* Wql = Wqh + WP;
    ushort* Wkh = Wql + WP;
    ushort* Wkl = Wkh + WP;
    ushort* Wvh = Wkl + WP;
    ushort* Wvl = Wvh + WP;
    ushort* Woh = Wvl + WP;
    ushort* Wol = Woh + WP;
    ushort* Qh  = Wol + WP;
    ushort* Ql  = Qh + NP;
    ushort* Kh  = Ql + NP;
    ushort* Kl  = Kh + NP;
    ushort* Vh  = Kl + NP;
    ushort* Rg  = Vh + NP;                    // 589,824 ushorts
    float*  Op1 = (float*)(Rg + 589824);      // NP floats
    float2* Ml0 = (float2*)(Op1 + NP);        // 32768 float2
    float2* Ml1 = Ml0 + 32768;
    float*  Op0 = (float*)d_ws;               // overlays Xh,Xl (dead after V GEMM)

    conv_pl<<<3072, 256, 0, stream>>>(x, Wq, Wk, Wv, Wo,
                                      Xh, Xl, Wqh, Wql, Wkh, Wkl, Wvh, Wvl, Woh, Wol);
    conv_rel<<<1152, 256, 0, stream>>>(rel, Rg);

    // Q and K projections fused via grid.z; K scaled by 1/8 at the source
    gemm_mfma<0, 2><<<dim3(8, 64, 2), 256, 0, stream>>>(
        Xh, Xl, Wqh, Wql, Wkh, Wkl, bq, bk, 1.0f, 0.125f,
        nullptr, Qh, Ql, Kh, Kl);
    // V projection, operand-swapped -> V^T hi plane
    gemm_mfma<0, 3><<<dim3(64, 8, 1), 256, 0, stream>>>(
        Wvh, Wvl, Xh, Xl, nullptr, nullptr, bv, nullptr, 1.0f, 1.0f,
        nullptr, Vh, nullptr, nullptr, nullptr);

    // split-K attention: O^T partials (Op0 overlays X planes, now dead)
    attn_mfma<<<dim3(8, 64, 2), 256, 0, stream>>>(
        Qh, Ql, Kh, Kl, Vh, Rg, Op0, Op1, Ml0, Ml1);

    // combine + transpose -> O planes (overlay Kh,Kl, dead after attn)
    attn_combine<<<dim3(8, 64), 256, 0, stream>>>(Op0, Op1, Ml0, Ml1, Kh, Kl);

    // output projection reads O planes (blocked layout), writes fp32
    gemm_mfma<1, 0><<<dim3(8, 64, 1), 256, 0, stream>>>(
        Kh, Kl, Woh, Wol, nullptr, nullptr, bo, nullptr, 1.0f, 1.0f,
        out, nullptr, nullptr, nullptr, nullptr);
}

// Round 8
// 94.251 us; speedup vs baseline: 1.1448x; 1.0862x over previous
//
#include <hip/hip_runtime.h>
#include <math.h>

#define B_  8
#define S_  512
#define D_  512
#define H_  8
#define DK_ 64

typedef __attribute__((ext_vector_type(8))) short short8;
typedef __attribute__((ext_vector_type(4))) float f32x4;

#define MFMA_BF16(a, b, c) __builtin_amdgcn_mfma_f32_16x16x32_bf16(a, b, c, 0, 0, 0)

__device__ __forceinline__ unsigned bf16_rne(float x) {
    unsigned u = __float_as_uint(x);
    return (u + 0x7FFFu + ((u >> 16) & 1u)) >> 16;
}
__device__ __forceinline__ float bf16f(unsigned h) { return __uint_as_float(h << 16); }

// async global->LDS, 16B per lane; lds dest = uniform base + lane*16
__device__ __forceinline__ void glds16(const ushort* g, ushort* l) {
    __builtin_amdgcn_global_load_lds(
        (const __attribute__((address_space(1))) unsigned int*)g,
        (__attribute__((address_space(3))) unsigned int*)l,
        16, 0, 0);
}

// ---------------------------------------------------------------------------
// fp32 -> split-bf16 planes for x and the four weight matrices (one launch)
// ---------------------------------------------------------------------------
__global__ __launch_bounds__(256)
void conv_pl(const float* __restrict__ x,
             const float* __restrict__ wq, const float* __restrict__ wk,
             const float* __restrict__ wv, const float* __restrict__ wo,
             ushort* __restrict__ Xh, ushort* __restrict__ Xl,
             ushort* __restrict__ Wqh, ushort* __restrict__ Wql,
             ushort* __restrict__ Wkh, ushort* __restrict__ Wkl,
             ushort* __restrict__ Wvh, ushort* __restrict__ Wvl,
             ushort* __restrict__ Woh, ushort* __restrict__ Wol) {
    const int bid = blockIdx.x;
    const float* src; ushort* dh; ushort* dl; int i4;
    if (bid < 2048) {
        src = x; dh = Xh; dl = Xl; i4 = bid * 256 + threadIdx.x;
    } else {
        const int r = bid - 2048;
        const int wsel = r >> 8;
        src = (wsel == 0) ? wq : (wsel == 1) ? wk : (wsel == 2) ? wv : wo;
        dh  = (wsel == 0) ? Wqh : (wsel == 1) ? Wkh : (wsel == 2) ? Wvh : Woh;
        dl  = (wsel == 0) ? Wql : (wsel == 1) ? Wkl : (wsel == 2) ? Wvl : Wol;
        i4 = (r & 255) * 256 + threadIdx.x;
    }
    const float4 v = ((const float4*)src)[i4];
    unsigned h[4], l[4];
    const float* vp = &v.x;
    #pragma unroll
    for (int j = 0; j < 4; ++j) { h[j] = bf16_rne(vp[j]); l[j] = bf16_rne(vp[j] - bf16f(h[j])); }
    ((uint2*)dh)[i4] = make_uint2(h[0] | (h[1] << 16), h[2] | (h[3] << 16));
    ((uint2*)dl)[i4] = make_uint2(l[0] | (l[1] << 16), l[2] | (l[3] << 16));
}

// ---------------------------------------------------------------------------
// rel_embed [1023][512] fp32 -> per-head padded bf16 table Rg[8][1152][64]
// ---------------------------------------------------------------------------
__global__ __launch_bounds__(256)
void conv_rel(const float* __restrict__ rel, ushort* __restrict__ Rg) {
    const int idx = blockIdx.x * 256 + threadIdx.x;
    const int d2 = idx & 31;
    const int rr = (idx >> 5) % 1152;
    const int h  = idx / (1152 * 32);
    unsigned v0 = 0, v1 = 0;
    if (rr >= 64 && rr < 64 + 1023) {
        const float* s = &rel[(size_t)(rr - 64) * 512 + h * 64 + d2 * 2];
        v0 = bf16_rne(s[0]); v1 = bf16_rne(s[1]);
    }
    *(uint*)&Rg[((size_t)h * 1152 + rr) * 64 + d2 * 2] = v0 | (v1 << 16);
}

// ---------------------------------------------------------------------------
// Split-bf16 MFMA GEMM: D = X . Y^T (+bias)*scale, K=512, tile 64x64, 4 waves.
// XB: 0 = X row-major; 1 = X planes in (b,h,s,dk) blocked layout
// OM: 0 = fp32 row-major out; 2 = split planes (b,h,s,dk); 3 = V^T hi-plane only
// ---------------------------------------------------------------------------
template<int XB, int OM>
__global__ __launch_bounds__(256, 2)
void gemm_mfma(const ushort* __restrict__ Xhp, const ushort* __restrict__ Xlp,
               const ushort* __restrict__ Yh0, const ushort* __restrict__ Yl0,
               const ushort* __restrict__ Yh1, const ushort* __restrict__ Yl1,
               const float* __restrict__ bias0, const float* __restrict__ bias1,
               float scale0, float scale1,
               float* __restrict__ outF,
               ushort* __restrict__ oh0, ushort* __restrict__ ol0,
               ushort* __restrict__ oh1, ushort* __restrict__ ol1) {
    __shared__ ushort Xs[2][2][64 * 64];
    __shared__ ushort Ys[2][2][64 * 64];

    const int z = blockIdx.z;
    const ushort* Yhp = z ? Yh1 : Yh0;
    const ushort* Ylp = z ? Yl1 : Yl0;
    const float*  bias = z ? bias1 : bias0;
    const float   scale = z ? scale1 : scale0;
    ushort* ohp = z ? oh1 : oh0;
    ushort* olp = z ? ol1 : ol0;

    const int tid = threadIdx.x;
    const int w = tid >> 6, lane = tid & 63;
    const int g = lane >> 4, c = lane & 15;
    const int rloc = lane >> 3, cc8 = lane & 7;
    const int cp = cc8 ^ rloc;
    const int r0 = blockIdx.y * 64;
    const int c0 = blockIdx.x * 64;

    const f32x4 fz = {0.f, 0.f, 0.f, 0.f};
    f32x4 acc[2][2] = {{fz, fz}, {fz, fz}};

    auto stage = [&](int kt, int buf) {
        const int k0 = kt * 64;
        const ushort* gb; ushort* lb; size_t rstr;
        if (w < 2) {
            const ushort* Xp = (w == 1) ? Xlp : Xhp;
            if (XB == 0) { gb = Xp + (size_t)r0 * 512 + k0; rstr = 512; }
            else {
                const int b = r0 >> 9, s0 = r0 & 511, h = k0 >> 6;
                gb = Xp + (((size_t)(b * 8 + h)) * 512 + s0) * 64; rstr = 64;
            }
            lb = &Xs[buf][w][0];
        } else {
            gb = ((w == 2) ? Yhp : Ylp) + (size_t)c0 * 512 + k0; rstr = 512;
            lb = &Ys[buf][w - 2][0];
        }
        #pragma unroll
        for (int j = 0; j < 8; ++j)
            glds16(gb + (size_t)(j * 8 + rloc) * rstr + cp * 8, lb + j * 512);
    };

    auto compute = [&](int buf) {
        #pragma unroll
        for (int ks = 0; ks < 2; ++ks) {
            short8 axh[2], axl[2], byh[2], byl[2];
            const int wm = (w >> 1) * 32, wn = (w & 1) * 32;
            #pragma unroll
            for (int t = 0; t < 2; ++t) {
                int row = wm + t * 16 + c;
                int off = row * 64 + (((ks * 4 + g) ^ (row & 7)) * 8);
                axh[t] = *(const short8*)&Xs[buf][0][off];
                axl[t] = *(const short8*)&Xs[buf][1][off];
                row = wn + t * 16 + c;
                off = row * 64 + (((ks * 4 + g) ^ (row & 7)) * 8);
                byh[t] = *(const short8*)&Ys[buf][0][off];
                byl[t] = *(const short8*)&Ys[buf][1][off];
            }
            #pragma unroll
            for (int tm = 0; tm < 2; ++tm)
                #pragma unroll
                for (int tn = 0; tn < 2; ++tn) {
                    acc[tm][tn] = MFMA_BF16(axh[tm], byh[tn], acc[tm][tn]);
                    acc[tm][tn] = MFMA_BF16(axl[tm], byh[tn], acc[tm][tn]);
                    acc[tm][tn] = MFMA_BF16(axh[tm], byl[tn], acc[tm][tn]);
                }
        }
    };

    stage(0, 0);
    __syncthreads();
    for (int kt = 0; kt < 8; ++kt) {
        if (kt < 7) stage(kt + 1, (kt + 1) & 1);
        compute(kt & 1);
        __syncthreads();
    }

    const int wm = (w >> 1) * 32, wn = (w & 1) * 32;
    if (OM == 0) {
        #pragma unroll
        for (int tn = 0; tn < 2; ++tn) {
            const int gc = c0 + wn + tn * 16 + c;
            const float bv = bias[gc];
            #pragma unroll
            for (int tm = 0; tm < 2; ++tm)
                #pragma unroll
                for (int i = 0; i < 4; ++i) {
                    const int gr = r0 + wm + tm * 16 + g * 4 + i;
                    outF[(size_t)gr * 512 + gc] = acc[tm][tn][i] + bv;
                }
        }
    } else if (OM == 2) {
        #pragma unroll
        for (int tn = 0; tn < 2; ++tn) {
            const int gc = c0 + wn + tn * 16 + c;
            const int h = gc >> 6, dk = gc & 63;
            const float bv = bias[gc];
            #pragma unroll
            for (int tm = 0; tm < 2; ++tm)
                #pragma unroll
                for (int i = 0; i < 4; ++i) {
                    const int gr = r0 + wm + tm * 16 + g * 4 + i;
                    const int b = gr >> 9, s = gr & 511;
                    const float v = (acc[tm][tn][i] + bv) * scale;
                    const unsigned hb = bf16_rne(v);
                    const size_t a = (((size_t)(b * 8 + h)) * 512 + s) * 64 + dk;
                    ohp[a] = (ushort)hb;
                    olp[a] = (ushort)bf16_rne(v - bf16f(hb));
                }
        }
    } else { // OM == 3: V^T, hi plane only
        #pragma unroll
        for (int tm = 0; tm < 2; ++tm)
            #pragma unroll
            for (int i = 0; i < 4; ++i) {
                const int gr = r0 + wm + tm * 16 + g * 4 + i;
                const int h = gr >> 6, dk = gr & 63;
                const float bv = bias[gr];
                #pragma unroll
                for (int tn = 0; tn < 2; ++tn) {
                    const int gc = c0 + wn + tn * 16 + c;
                    const int b = gc >> 9, s = gc & 511;
                    const float v = acc[tm][tn][i] + bv;
                    const size_t a = (((size_t)(b * 8 + h)) * 64 + dk) * 512 + s;
                    ohp[a] = (ushort)bf16_rne(v);
                }
            }
    }
}

// ---------------------------------------------------------------------------
// MFMA flash attention, lane-local softmax (S^T = mfma(K,Q), permuted keys).
// R8 change vs R5 (passing): the U-tile rel reads come from an LDS-staged
// 128-row band (Rsm) instead of global. R5's global B-frag reads touched 64
// cache lines per instruction (row stride 128B) -> TA-serialized. Rsm is
// staged with PLAIN vector loads + ds_write (no global_load_lds for this
// buffer), XOR-chunk swizzle; everything else is verbatim R5.
// Rsm row r holds padded rel row (k0 - qwb + 512 + r); wave w reads rows
// rl = 48 - 16w + c + 16ut  ==  R5's global row (k0 - qw + 560 + c + 16ut).
// ---------------------------------------------------------------------------
__global__ __launch_bounds__(256, 2)
void attn_mfma(const ushort* __restrict__ Qhp, const ushort* __restrict__ Qlp,
               const ushort* __restrict__ Khp, const ushort* __restrict__ Klp,
               const ushort* __restrict__ Vhp, const ushort* __restrict__ Rg,
               float* __restrict__ Op0, float* __restrict__ Op1,
               float2* __restrict__ Ml0, float2* __restrict__ Ml1) {
    __shared__ ushort Ksm[2][64 * 64];   // 16 KB, key rows PERMUTED
    __shared__ ushort Vsm[64 * 64];      //  8 KB [dk][key] (V^T)
    __shared__ ushort Rsm[128 * 64];     // 16 KB rel band, chunk-swizzled
    __shared__ ushort Usm[4][16 * 86];   // 11 KB per-wave bias rows

    const int tid  = threadIdx.x;
    const int w    = tid >> 6;
    const int lane = tid & 63;
    const int g    = lane >> 4;
    const int c    = lane & 15;
    const int rloc = lane >> 3, cc8 = lane & 7;
    const int bh   = blockIdx.y;
    const int h    = bh & 7;
    const int z    = blockIdx.z;
    const int qwb  = blockIdx.x * 64;
    const int qw   = qwb + w * 16;

    float* __restrict__ Op = z ? Op1 : Op0;
    float2* __restrict__ Ml = z ? Ml1 : Ml0;

    short8 qfh[2], qfl[2];
    #pragma unroll
    for (int ks = 0; ks < 2; ++ks) {
        const size_t qi = ((size_t)bh * 512 + qw + c) * 64 + ks * 32 + g * 8;
        qfh[ks] = *(const short8*)&Qhp[qi];
        qfl[ks] = *(const short8*)&Qlp[qi];
    }

    const f32x4 fz = {0.f, 0.f, 0.f, 0.f};
    f32x4 o[4] = {fz, fz, fz, fz};      // O^T: row d = 16dt+4g+i, col q = c
    float m = -INFINITY, l = 0.f;

    const ushort* KhB = Khp + (size_t)bh * 512 * 64;
    const ushort* KlB = Klp + (size_t)bh * 512 * 64;
    const ushort* VhB = Vhp + (size_t)bh * 64 * 512;
    const ushort* RgH = Rg + (size_t)h * 1152 * 64;

    for (int kt = z * 4; kt < z * 4 + 4; ++kt) {
        const int k0 = kt * 64;
        const int rbase = k0 - qwb + 512;   // in [64, 960]
        __syncthreads();

        // ---- rel band -> Rsm: plain coalesced loads + swizzled ds_write ----
        #pragma unroll
        for (int j = 0; j < 4; ++j) {
            const int cd  = j * 256 + tid;        // 1024 chunks = 128 rows x 8
            const int row = cd >> 3, cc = cd & 7;
            const uint4 v = *(const uint4*)&RgH[(size_t)(rbase + row) * 64 + cc * 8];
            *(uint4*)&Rsm[row * 64 + ((cc ^ (row & 7)) << 3)] = v;
        }

        // ---- stage K planes (key-permuted) / V^T via glds (R5 pattern) ----
        if (w < 2) {
            const ushort* gb = (w == 0) ? KhB : KlB;
            ushort* lb = &Ksm[w][0];
            #pragma unroll
            for (int j = 0; j < 8; ++j) {
                const int row = j * 8 + rloc;              // LDS row
                const int tcq = row >> 4, cq = row & 15;
                const int key = ((tcq & 1) << 5) + ((cq >> 2) << 3)
                              + ((tcq >> 1) << 2) + (cq & 3);
                glds16(gb + (size_t)(k0 + key) * 64 + ((cc8 ^ rloc) << 3),
                       lb + j * 512);
            }
        } else {
            const ushort* gb = VhB + k0 + (size_t)(w - 2) * 32 * 512;
            ushort* lb = &Vsm[(w - 2) * 32 * 64];
            #pragma unroll
            for (int j = 0; j < 4; ++j)
                glds16(gb + (size_t)(j * 8 + rloc) * 512 + ((cc8 ^ rloc) << 3),
                       lb + j * 512);
        }
        __syncthreads();

        // ---- U tiles: U[q][delta] (1-term) from LDS rel band ----
        f32x4 u[5];
        #pragma unroll
        for (int ut = 0; ut < 5; ++ut) u[ut] = fz;
        #pragma unroll
        for (int ks = 0; ks < 2; ++ks)
            #pragma unroll
            for (int ut = 0; ut < 5; ++ut) {
                const int rl = 48 - 16 * w + c + ut * 16;
                const short8 rf = *(const short8*)
                    &Rsm[rl * 64 + (((ks * 4 + g) ^ (c & 7)) << 3)];
                u[ut] = MFMA_BF16(qfh[ks], rf, u[ut]);
            }
        #pragma unroll
        for (int ut = 0; ut < 5; ++ut)
            #pragma unroll
            for (int i = 0; i < 4; ++i)
                Usm[w][(g * 4 + i) * 86 + c + ut * 16] = (ushort)bf16_rne(u[ut][i]);

        // ---- S^T tiles: mfma(A=K permuted rows, B=Q), 3-term split ----
        f32x4 st[4];
        #pragma unroll
        for (int tc = 0; tc < 4; ++tc) st[tc] = fz;
        #pragma unroll
        for (int ks = 0; ks < 2; ++ks)
            #pragma unroll
            for (int tc = 0; tc < 4; ++tc) {
                const int row = tc * 16 + c;
                const int chv = ((ks * 4 + g) ^ (row & 7)) * 8;
                const short8 kh8 = *(const short8*)&Ksm[0][row * 64 + chv];
                const short8 kl8 = *(const short8*)&Ksm[1][row * 64 + chv];
                st[tc] = MFMA_BF16(kh8, qfh[ks], st[tc]);
                st[tc] = MFMA_BF16(kh8, qfl[ks], st[tc]);
                st[tc] = MFMA_BF16(kl8, qfh[ks], st[tc]);
            }

        asm volatile("s_waitcnt lgkmcnt(0)" ::: "memory");  // U writes visible

        // ---- bias add (scalar LDS reads, direct delta indexing) ----
        #pragma unroll
        for (int tc = 0; tc < 4; ++tc)
            #pragma unroll
            for (int i = 0; i < 4; ++i) {
                const int key = ((tc & 1) << 5) + 8 * g + ((tc >> 1) << 2) + i;
                st[tc][i] += bf16f(Usm[w][c * 85 + key + 15]);
            }

        // ---- lane-local online softmax ----
        float tm = fmaxf(fmaxf(st[0][0], st[0][1]), fmaxf(st[0][2], st[0][3]));
        #pragma unroll
        for (int tc = 1; tc < 4; ++tc) {
            const float t2 = fmaxf(fmaxf(st[tc][0], st[tc][1]),
                                   fmaxf(st[tc][2], st[tc][3]));
            tm = fmaxf(tm, t2);
        }
        tm = fmaxf(tm, __shfl_xor(tm, 16));
        tm = fmaxf(tm, __shfl_xor(tm, 32));
        const float mn = fmaxf(m, tm);
        const float corr = __expf(m - mn);
        m = mn;
        l *= corr;
        #pragma unroll
        for (int dt = 0; dt < 4; ++dt) o[dt] *= corr;

        uint pk[4][2];
        #pragma unroll
        for (int tc = 0; tc < 4; ++tc) {
            const float p0 = __expf(st[tc][0] - mn);
            const float p1 = __expf(st[tc][1] - mn);
            const float p2 = __expf(st[tc][2] - mn);
            const float p3 = __expf(st[tc][3] - mn);
            l += (p0 + p1) + (p2 + p3);
            pk[tc][0] = bf16_rne(p0) | (bf16_rne(p1) << 16);
            pk[tc][1] = bf16_rne(p2) | (bf16_rne(p3) << 16);
        }

        // ---- PV: O^T += mfma(A=V^T, B=P^T); B-frag is lane-local ----
        #pragma unroll
        for (int ks = 0; ks < 2; ++ks) {
            union { uint u4[4]; short8 s8; } pb;
            pb.u4[0] = pk[ks][0];
            pb.u4[1] = pk[ks][1];
            pb.u4[2] = pk[ks + 2][0];
            pb.u4[3] = pk[ks + 2][1];
            #pragma unroll
            for (int dt = 0; dt < 4; ++dt) {
                const int row = dt * 16 + c;
                const int chv = ((ks * 4 + g) ^ (row & 7)) * 8;
                const short8 vh8 = *(const short8*)&Vsm[row * 64 + chv];
                o[dt] = MFMA_BF16(vh8, pb.s8, o[dt]);
            }
        }
    }

    // ---- epilogue: reduce l over g-groups, store O^T partial + (m,l) ----
    float lt = l;
    lt += __shfl_xor(lt, 16);
    lt += __shfl_xor(lt, 32);
    if (lane < 16) Ml[(size_t)bh * 512 + qw + c] = make_float2(m, lt);
    #pragma unroll
    for (int dt = 0; dt < 4; ++dt)
        #pragma unroll
        for (int i = 0; i < 4; ++i)
            Op[((size_t)bh * 64 + dt * 16 + g * 4 + i) * 512 + qw + c] = o[dt][i];
}

// ---------------------------------------------------------------------------
// merge split-K halves, transpose O^T -> (b,h,s,dk), emit split-bf16 O planes
// ---------------------------------------------------------------------------
__global__ __launch_bounds__(256)
void attn_combine(const float* __restrict__ Op0, const float* __restrict__ Op1,
                  const float2* __restrict__ Ml0, const float2* __restrict__ Ml1,
                  ushort* __restrict__ Oh, ushort* __restrict__ Ol) {
    __shared__ float L0[64][67];
    __shared__ float L1[64][67];
    const int t = threadIdx.x;
    const int bh = blockIdx.y;
    const int s0 = blockIdx.x * 64;
    #pragma unroll
    for (int j = 0; j < 4; ++j) {
        const int d = (t >> 4) + j * 16;
        const int c4 = (t & 15) * 4;
        const size_t ga = ((size_t)bh * 64 + d) * 512 + s0 + c4;
        *(float4*)&L0[d][c4] = *(const float4*)&Op0[ga];
        *(float4*)&L1[d][c4] = *(const float4*)&Op1[ga];
    }
    __syncthreads();
    const int sl = t >> 2;
    const int d0 = (t & 3) * 16;
    const float2 a = Ml0[(size_t)bh * 512 + s0 + sl];
    const float2 b = Ml1[(size_t)bh * 512 + s0 + sl];
    const float mm = fmaxf(a.x, b.x);
    float w0 = __expf(a.x - mm), w1 = __expf(b.x - mm);
    const float inv = 1.0f / (a.y * w0 + b.y * w1);
    w0 *= inv; w1 *= inv;
    const size_t ob = ((size_t)bh * 512 + s0 + sl) * 64 + d0;
    #pragma unroll
    for (int q = 0; q < 4; ++q) {
        unsigned hb[4], lb4[4];
        #pragma unroll
        for (int e = 0; e < 4; ++e) {
            const int dd = q * 4 + e;
            const float v = L0[d0 + dd][sl] * w0 + L1[d0 + dd][sl] * w1;
            hb[e] = bf16_rne(v);
            lb4[e] = bf16_rne(v - bf16f(hb[e]));
        }
        *(uint2*)&Oh[ob + q * 4] = make_uint2(hb[0] | (hb[1] << 16), hb[2] | (hb[3] << 16));
        *(uint2*)&Ol[ob + q * 4] = make_uint2(lb4[0] | (lb4[1] << 16), lb4[2] | (lb4[3] << 16));
    }
}

// ---------------------------------------------------------------------------
extern "C" void kernel_launch(void* const* d_in, const int* in_sizes, int n_in,
                              void* d_out, int out_size, void* d_ws, size_t ws_size,
                              hipStream_t stream) {
    const float* x   = (const float*)d_in[0];
    const float* Wq  = (const float*)d_in[1];
    const float* bq  = (const float*)d_in[2];
    const float* Wk  = (const float*)d_in[3];
    const float* bk  = (const float*)d_in[4];
    const float* Wv  = (const float*)d_in[5];
    const float* bv  = (const float*)d_in[6];
    const float* Wo  = (const float*)d_in[7];
    const float* bo  = (const float*)d_in[8];
    const float* rel = (const float*)d_in[9];
    float* out = (float*)d_out;

    const size_t NP = (size_t)B_ * H_ * S_ * DK_;   // 2,097,152
    const size_t WP = (size_t)D_ * D_;              //   262,144
    ushort* Xh  = (ushort*)d_ws;
    ushort* Xl  = Xh + NP;
    ushort* Wqh = Xl + NP;
    ushort* Wql = Wqh + WP;
    ushort* Wkh = Wql + WP;
    ushort* Wkl = Wkh + WP;
    ushort* Wvh = Wkl + WP;
    ushort* Wvl = Wvh + WP;
    ushort* Woh = Wvl + WP;
    ushort* Wol = Woh + WP;
    ushort* Qh  = Wol + WP;
    ushort* Ql  = Qh + NP;
    ushort* Kh  = Ql + NP;
    ushort* Kl  = Kh + NP;
    ushort* Vh  = Kl + NP;
    ushort* Rg  = Vh + NP;                    // 589,824 ushorts
    float*  Op1 = (float*)(Rg + 589824);      // NP floats
    float2* Ml0 = (float2*)(Op1 + NP);        // 32768 float2
    float2* Ml1 = Ml0 + 32768;
    float*  Op0 = (float*)d_ws;               // overlays Xh,Xl (dead after proj)

    conv_pl<<<3072, 256, 0, stream>>>(x, Wq, Wk, Wv, Wo,
                                      Xh, Xl, Wqh, Wql, Wkh, Wkl, Wvh, Wvl, Woh, Wol);
    conv_rel<<<1152, 256, 0, stream>>>(rel, Rg);

    // Q and K projections fused via grid.z; K scaled by 1/8 at the source
    gemm_mfma<0, 2><<<dim3(8, 64, 2), 256, 0, stream>>>(
        Xh, Xl, Wqh, Wql, Wkh, Wkl, bq, bk, 1.0f, 0.125f,
        nullptr, Qh, Ql, Kh, Kl);
    // V projection, operand-swapped -> V^T hi plane
    gemm_mfma<0, 3><<<dim3(64, 8, 1), 256, 0, stream>>>(
        Wvh, Wvl, Xh, Xl, nullptr, nullptr, bv, nullptr, 1.0f, 1.0f,
        nullptr, Vh, nullptr, nullptr, nullptr);

    // split-K attention: O^T partials (Op0 overlays X planes, now dead)
    attn_mfma<<<dim3(8, 64, 2), 256, 0, stream>>>(
        Qh, Ql, Kh, Kl, Vh, Rg, Op0, Op1, Ml0, Ml1);

    // combine + transpose -> O planes (overlay Kh,Kl, dead after attn)
    attn_combine<<<dim3(8, 64), 256, 0, stream>>>(Op0, Op1, Ml0, Ml1, Kh, Kl);

    // output projection reads O planes (blocked layout), writes fp32
    gemm_mfma<1, 0><<<dim3(8, 64, 1), 256, 0, stream>>>(
        Kh, Kl, Woh, Wol, nullptr, nullptr, bo, nullptr, 1.0f, 1.0f,
        out, nullptr, nullptr, nullptr, nullptr);
}